// Round 5
// baseline (1062.541 us; speedup 1.0000x reference)
//
#include <hip/hip_runtime.h>

#define NB 4
#define NH 16
#define SEQ 2048
#define DH 128
#define QT 128
#define KT 64
#define NTILES (SEQ / KT)
#define NTHREADS 512
#define LKS 136   /* K-tile row stride in halfs: 272 B rows, conflict-free b128 reads + 8B writes */

typedef __attribute__((ext_vector_type(8))) _Float16 f16x8;
typedef __attribute__((ext_vector_type(4))) _Float16 f16x4;
typedef __attribute__((ext_vector_type(2))) _Float16 f16x2;
typedef __attribute__((ext_vector_type(4))) float f32x4;

static __device__ __forceinline__ f16x2 pkrtz(float x, float y) {
    return __builtin_bit_cast(f16x2, __builtin_amdgcn_cvt_pkrtz(x, y));
}
static __device__ __forceinline__ unsigned ubits(f16x2 v) {
    return __builtin_bit_cast(unsigned, v);
}

// scale 1/0.32 and log2(e) folded into Q at load -> QK output already in exp2 domain
static constexpr float CLOG2E = 3.125f * 1.44269504088896340736f;

// V^T LDS layout [d][key] = [128][64] halfs, no pad. 8B-block swizzle:
// offset(halfs) = d*64 + ((k4 ^ dmix(d)) << 2), k4 = key/4, dmix = (d&15)^((d>>2)&15).
// Staging writes (d = 4*c4+i, k4 = r16) and PV reads (d = db*16+l15, k4 = 4g+quad)
// both map 16 lanes -> 16 distinct 8B bank-pairs => <=2-way (free).
static __device__ __forceinline__ int vt_off(int d, int k4) {
    int dmix = (d & 15) ^ ((d >> 2) & 15);
    return (d << 6) + (((k4 ^ dmix) & 15) << 2);
}

__global__ __launch_bounds__(NTHREADS, 4)
void fattn_kernel(const float* __restrict__ Q, const float* __restrict__ K,
                  const float* __restrict__ V, float* __restrict__ O) {
    __shared__ _Float16 lk[2][KT][LKS];      // K tile double buffer
    __shared__ _Float16 lvt[2][DH * KT];     // V^T tile double buffer (swizzled)

    const int tid  = threadIdx.x;
    const int wave = tid >> 6;
    const int lane = tid & 63;
    const int l15  = lane & 15;
    const int quad = lane >> 4;

    // XCD swizzle: all 16 Q-tiles of one (b,h) on one XCD (K/V L2 locality).
    const int blk = blockIdx.x;              // 0..1023
    const int j   = blk >> 3;                // 0..127
    const int bh  = (blk & 7) + 8 * (j >> 4);
    const int qt  = j & 15;

    const size_t base = (size_t)bh * SEQ * DH;
    const float* Qb = Q + base;
    const float* Kb = K + base;
    const float* Vb = V + base;
    float*       Ob = O + base;

    // ---- Q fragments, B-operand layout: lane holds Q[q=l15][d=ks*32+quad*8+j], pre-scaled ----
    f16x8 qf[4];
    {
        const int qrow = qt * QT + wave * 16 + l15;
        const float* qp = Qb + (size_t)qrow * DH + quad * 8;
#pragma unroll
        for (int ks = 0; ks < 4; ++ks) {
            float4 a = *(const float4*)(qp + ks * 32);
            float4 b = *(const float4*)(qp + ks * 32 + 4);
            f16x2 p0 = pkrtz(a.x * CLOG2E, a.y * CLOG2E);
            f16x2 p1 = pkrtz(a.z * CLOG2E, a.w * CLOG2E);
            f16x2 p2 = pkrtz(b.x * CLOG2E, b.y * CLOG2E);
            f16x2 p3 = pkrtz(b.z * CLOG2E, b.w * CLOG2E);
            qf[ks] = (f16x8){p0.x, p0.y, p1.x, p1.y, p2.x, p2.y, p3.x, p3.y};
        }
    }

    f32x4 oacc[8];
#pragma unroll
    for (int db = 0; db < 8; ++db) oacc[db] = (f32x4){0.f, 0.f, 0.f, 0.f};
    float m_i = -3.0e38f;   // softmax state of q-row l15 (replicated over quads)
    float l_i = 0.f;

    // staging decomposition: 512 threads, tile = 64 rows x 128 cols fp32
    const int c4  = tid & 31;   // float4 column
    const int r16 = tid >> 5;   // rows r16*4 .. r16*4+3

    float4 kpf[4], vpf[4];
    // ---- preamble: tile 0 -> regs -> buf0 ----
    {
        const float* kp = Kb + (size_t)(r16 * 4) * DH + c4 * 4;
        const float* vp = Vb + (size_t)(r16 * 4) * DH + c4 * 4;
#pragma unroll
        for (int p = 0; p < 4; ++p) {
            kpf[p] = *(const float4*)(kp + (size_t)p * DH);
            vpf[p] = *(const float4*)(vp + (size_t)p * DH);
        }
        unsigned vh[4][2];
#pragma unroll
        for (int p = 0; p < 4; ++p) {
            const int r = r16 * 4 + p;
            uint2 kw;
            kw.x = ubits(pkrtz(kpf[p].x, kpf[p].y));
            kw.y = ubits(pkrtz(kpf[p].z, kpf[p].w));
            *(uint2*)&lk[0][r][c4 * 4] = kw;
            vh[p][0] = ubits(pkrtz(vpf[p].x, vpf[p].y));
            vh[p][1] = ubits(pkrtz(vpf[p].z, vpf[p].w));
        }
#pragma unroll
        for (int i = 0; i < 4; ++i) {
            const int jw = i >> 1, sh = (i & 1) * 16;
            uint2 w;
            w.x = ((vh[0][jw] >> sh) & 0xFFFFu) | (((vh[1][jw] >> sh) & 0xFFFFu) << 16);
            w.y = ((vh[2][jw] >> sh) & 0xFFFFu) | (((vh[3][jw] >> sh) & 0xFFFFu) << 16);
            *(uint2*)&lvt[0][vt_off(c4 * 4 + i, r16)] = w;
        }
    }
    __syncthreads();
    // issue tile 1 loads
    {
        const float* kp = Kb + (size_t)(KT + r16 * 4) * DH + c4 * 4;
        const float* vp = Vb + (size_t)(KT + r16 * 4) * DH + c4 * 4;
#pragma unroll
        for (int p = 0; p < 4; ++p) {
            kpf[p] = *(const float4*)(kp + (size_t)p * DH);
            vpf[p] = *(const float4*)(vp + (size_t)p * DH);
        }
    }

    for (int it = 0; it < NTILES; ++it) {
        const int cur = it & 1, nxt = cur ^ 1;

        // ---- S^T = K . Q^T : out lane holds S[q=l15][key = g*16+quad*4+r] ----
        f32x4 sacc[4];
#pragma unroll
        for (int g = 0; g < 4; ++g) sacc[g] = (f32x4){0.f, 0.f, 0.f, 0.f};
#pragma unroll
        for (int g = 0; g < 4; ++g) {
#pragma unroll
            for (int ks = 0; ks < 4; ++ks) {
                f16x8 kf = *(const f16x8*)&lk[cur][g * 16 + l15][ks * 32 + quad * 8];
                sacc[g] = __builtin_amdgcn_mfma_f32_16x16x32_f16(kf, qf[ks], sacc[g], 0, 0, 0);
            }
        }

        // ---- online softmax: 16 in-register values + 2 shuffles ----
        float mx = sacc[0][0];
#pragma unroll
        for (int g = 0; g < 4; ++g)
#pragma unroll
            for (int r = 0; r < 4; ++r) mx = fmaxf(mx, sacc[g][r]);
        mx = fmaxf(mx, __shfl_xor(mx, 16));
        mx = fmaxf(mx, __shfl_xor(mx, 32));
        const float mnew = fmaxf(m_i, mx);
        const float alpha = __builtin_amdgcn_exp2f(m_i - mnew);
        m_i = mnew;

        float ps[4][4];
        float rs = 0.f;
#pragma unroll
        for (int g = 0; g < 4; ++g)
#pragma unroll
            for (int r = 0; r < 4; ++r) {
                ps[g][r] = __builtin_amdgcn_exp2f(sacc[g][r] - m_i);
                rs += ps[g][r];
            }
        rs += __shfl_xor(rs, 16);
        rs += __shfl_xor(rs, 32);
        l_i = l_i * alpha + rs;

        // ---- stage tile it+1 regs -> buf[nxt] (overlaps with PV below; no barrier needed) ----
        if (it + 1 < NTILES) {
            unsigned vh[4][2];
#pragma unroll
            for (int p = 0; p < 4; ++p) {
                const int r = r16 * 4 + p;
                uint2 kw;
                kw.x = ubits(pkrtz(kpf[p].x, kpf[p].y));
                kw.y = ubits(pkrtz(kpf[p].z, kpf[p].w));
                *(uint2*)&lk[nxt][r][c4 * 4] = kw;
                vh[p][0] = ubits(pkrtz(vpf[p].x, vpf[p].y));
                vh[p][1] = ubits(pkrtz(vpf[p].z, vpf[p].w));
            }
#pragma unroll
            for (int i = 0; i < 4; ++i) {
                const int jw = i >> 1, sh = (i & 1) * 16;
                uint2 w;
                w.x = ((vh[0][jw] >> sh) & 0xFFFFu) | (((vh[1][jw] >> sh) & 0xFFFFu) << 16);
                w.y = ((vh[2][jw] >> sh) & 0xFFFFu) | (((vh[3][jw] >> sh) & 0xFFFFu) << 16);
                *(uint2*)&lvt[nxt][vt_off(c4 * 4 + i, r16)] = w;
            }
        }

        // ---- rescale O (alpha of rows quad*4+r via shuffle) ----
        float af[4];
#pragma unroll
        for (int r = 0; r < 4; ++r) af[r] = __shfl(alpha, (lane & 48) | (quad * 4 + r));
#pragma unroll
        for (int db = 0; db < 8; ++db)
#pragma unroll
            for (int r = 0; r < 4; ++r) oacc[db][r] *= af[r];

        // ---- O += P.V : A = P (regs), B = V^T from lvt[cur] ----
        f16x4 pf[4];
#pragma unroll
        for (int g = 0; g < 4; ++g)
            pf[g] = (f16x4){(_Float16)ps[g][0], (_Float16)ps[g][1],
                            (_Float16)ps[g][2], (_Float16)ps[g][3]};
#pragma unroll
        for (int db = 0; db < 8; ++db) {
            const int d = db * 16 + l15;
#pragma unroll
            for (int g = 0; g < 4; ++g) {
                f16x4 vb = *(const f16x4*)&lvt[cur][vt_off(d, 4 * g + quad)];
                oacc[db] = __builtin_amdgcn_mfma_f32_16x16x16f16(pf[g], vb, oacc[db], 0, 0, 0);
            }
        }

        // ---- issue tile it+2 loads (regs free after staging write above) ----
        if (it + 2 < NTILES) {
            const float* kp = Kb + (size_t)((it + 2) * KT + r16 * 4) * DH + c4 * 4;
            const float* vp = Vb + (size_t)((it + 2) * KT + r16 * 4) * DH + c4 * 4;
#pragma unroll
            for (int p = 0; p < 4; ++p) {
                kpf[p] = *(const float4*)(kp + (size_t)p * DH);
                vpf[p] = *(const float4*)(vp + (size_t)p * DH);
            }
        }

        __syncthreads();   // single barrier per iteration
    }

    // ---- epilogue ----
    const float inv = 1.0f / l_i;
    float invr[4];
#pragma unroll
    for (int r = 0; r < 4; ++r) invr[r] = __shfl(inv, (lane & 48) | (quad * 4 + r));
#pragma unroll
    for (int db = 0; db < 8; ++db)
#pragma unroll
        for (int r = 0; r < 4; ++r) {
            const int row = qt * QT + wave * 16 + quad * 4 + r;
            const int col = db * 16 + l15;
            Ob[(size_t)row * DH + col] = oacc[db][r] * invr[r];
        }
}

extern "C" void kernel_launch(void* const* d_in, const int* in_sizes, int n_in,
                              void* d_out, int out_size, void* d_ws, size_t ws_size,
                              hipStream_t stream) {
    const float* Q = (const float*)d_in[0];
    const float* K = (const float*)d_in[1];
    const float* V = (const float*)d_in[2];
    float* O = (float*)d_out;
    // masks (d_in[3..5]) and dropout_p (d_in[6]) unused per reference.
    const int nblocks = NB * NH * (SEQ / QT);   // 1024
    fattn_kernel<<<dim3(nblocks), dim3(NTHREADS), 0, stream>>>(Q, K, V, O);
}

// Round 6
// 660.369 us; speedup vs baseline: 1.6090x; 1.6090x over previous
//
#include <hip/hip_runtime.h>

#define NB 4
#define NH 16
#define SEQ 2048
#define DH 128
#define QT 128
#define KT 64
#define NTILES (SEQ / KT)
#define NTHREADS 512
#define LKS 136   /* K-tile row stride in halfs */

typedef __attribute__((ext_vector_type(8))) _Float16 f16x8;
typedef __attribute__((ext_vector_type(4))) _Float16 f16x4;
typedef __attribute__((ext_vector_type(2))) _Float16 f16x2;
typedef __attribute__((ext_vector_type(4))) float f32x4;

static __device__ __forceinline__ f16x2 pkrtz(float x, float y) {
    return __builtin_bit_cast(f16x2, __builtin_amdgcn_cvt_pkrtz(x, y));
}
static __device__ __forceinline__ unsigned ubits(f16x2 v) {
    return __builtin_bit_cast(unsigned, v);
}

// scale 1/0.32 and log2(e) folded into Q at load -> QK output already in exp2 domain
static constexpr float CLOG2E = 3.125f * 1.44269504088896340736f;

// V^T LDS layout [d][key] = [128][64] halfs, 8B-block swizzle (see R5 derivation).
static __device__ __forceinline__ int vt_off(int d, int k4) {
    int dmix = (d & 15) ^ ((d >> 2) & 15);
    return (d << 6) + (((k4 ^ dmix) & 15) << 2);
}

__global__ __launch_bounds__(NTHREADS, 4)
void fattn_kernel(const float* __restrict__ Q, const float* __restrict__ K,
                  const float* __restrict__ V, float* __restrict__ O) {
    __shared__ _Float16 lk[2][KT][LKS];      // K tile double buffer
    __shared__ _Float16 lvt[2][DH * KT];     // V^T tile double buffer (swizzled)

    const int tid  = threadIdx.x;
    const int wave = tid >> 6;
    const int lane = tid & 63;
    const int l15  = lane & 15;
    const int quad = lane >> 4;

    // XCD swizzle: all 16 Q-tiles of one (b,h) on one XCD (K/V L2 locality).
    const int blk = blockIdx.x;              // 0..1023
    const int j   = blk >> 3;                // 0..127
    const int bh  = (blk & 7) + 8 * (j >> 4);
    const int qt  = j & 15;

    const size_t base = (size_t)bh * SEQ * DH;
    const float* Qb = Q + base;
    const float* Kb = K + base;
    const float* Vb = V + base;
    float*       Ob = O + base;

    // ---- Q fragments, B-operand layout: lane holds Q[q=l15][d=ks*32+quad*8+j], pre-scaled ----
    f16x8 qf[4];
    {
        const int qrow = qt * QT + wave * 16 + l15;
        const float* qp = Qb + (size_t)qrow * DH + quad * 8;
#pragma unroll
        for (int ks = 0; ks < 4; ++ks) {
            float4 a = *(const float4*)(qp + ks * 32);
            float4 b = *(const float4*)(qp + ks * 32 + 4);
            f16x2 p0 = pkrtz(a.x * CLOG2E, a.y * CLOG2E);
            f16x2 p1 = pkrtz(a.z * CLOG2E, a.w * CLOG2E);
            f16x2 p2 = pkrtz(b.x * CLOG2E, b.y * CLOG2E);
            f16x2 p3 = pkrtz(b.z * CLOG2E, b.w * CLOG2E);
            qf[ks] = (f16x8){p0.x, p0.y, p1.x, p1.y, p2.x, p2.y, p3.x, p3.y};
        }
    }

    f32x4 oacc[8];
#pragma unroll
    for (int db = 0; db < 8; ++db) oacc[db] = (f32x4){0.f, 0.f, 0.f, 0.f};
    float m_i = -3.0e38f;   // softmax state of q-row l15 (replicated over quads)
    float l_i = 0.f;

    // staging decomposition: 512 threads, tile = 64 rows x 128 cols fp32
    const int c4  = tid & 31;   // float4 column
    const int r16 = tid >> 5;   // rows r16*4 .. r16*4+3

    float4 kpf[4], vpf[4];
    // ---- preamble: tile 0 -> regs -> buf0 ----
    {
        const float* kp = Kb + (size_t)(r16 * 4) * DH + c4 * 4;
        const float* vp = Vb + (size_t)(r16 * 4) * DH + c4 * 4;
#pragma unroll
        for (int p = 0; p < 4; ++p) {
            kpf[p] = *(const float4*)(kp + (size_t)p * DH);
            vpf[p] = *(const float4*)(vp + (size_t)p * DH);
        }
        unsigned vh[4][2];
#pragma unroll
        for (int p = 0; p < 4; ++p) {
            const int r = r16 * 4 + p;
            uint2 kw;
            kw.x = ubits(pkrtz(kpf[p].x, kpf[p].y));
            kw.y = ubits(pkrtz(kpf[p].z, kpf[p].w));
            *(uint2*)&lk[0][r][c4 * 4] = kw;
            vh[p][0] = ubits(pkrtz(vpf[p].x, vpf[p].y));
            vh[p][1] = ubits(pkrtz(vpf[p].z, vpf[p].w));
        }
#pragma unroll
        for (int i = 0; i < 4; ++i) {
            const int jw = i >> 1, sh = (i & 1) * 16;
            uint2 w;
            w.x = ((vh[0][jw] >> sh) & 0xFFFFu) | (((vh[1][jw] >> sh) & 0xFFFFu) << 16);
            w.y = ((vh[2][jw] >> sh) & 0xFFFFu) | (((vh[3][jw] >> sh) & 0xFFFFu) << 16);
            *(uint2*)&lvt[0][vt_off(c4 * 4 + i, r16)] = w;
        }
    }
    __syncthreads();

    for (int it = 0; it < NTILES; ++it) {
        const int cur = it & 1, nxt = cur ^ 1;
        const bool more = (it + 1) < NTILES;

        // ---- issue tile it+1 loads FIRST (full-iteration latency cover; the
        //      consuming staging sits at the bottom, before the barrier) ----
        if (more) {
            const float* kp = Kb + (size_t)((it + 1) * KT + r16 * 4) * DH + c4 * 4;
            const float* vp = Vb + (size_t)((it + 1) * KT + r16 * 4) * DH + c4 * 4;
#pragma unroll
            for (int p = 0; p < 4; ++p) {
                kpf[p] = *(const float4*)(kp + (size_t)p * DH);
                vpf[p] = *(const float4*)(vp + (size_t)p * DH);
            }
        }

        // ---- S^T = K . Q^T : out lane holds S[q=l15][key = g*16+quad*4+r] ----
        f32x4 sacc[4];
#pragma unroll
        for (int g = 0; g < 4; ++g) sacc[g] = (f32x4){0.f, 0.f, 0.f, 0.f};
#pragma unroll
        for (int g = 0; g < 4; ++g) {
#pragma unroll
            for (int ks = 0; ks < 4; ++ks) {
                f16x8 kf = *(const f16x8*)&lk[cur][g * 16 + l15][ks * 32 + quad * 8];
                sacc[g] = __builtin_amdgcn_mfma_f32_16x16x32_f16(kf, qf[ks], sacc[g], 0, 0, 0);
            }
        }

        // ---- stage K regs -> lk[nxt] (K loads covered by QK; frees 16 VGPRs) ----
        if (more) {
#pragma unroll
            for (int p = 0; p < 4; ++p) {
                const int r = r16 * 4 + p;
                uint2 kw;
                kw.x = ubits(pkrtz(kpf[p].x, kpf[p].y));
                kw.y = ubits(pkrtz(kpf[p].z, kpf[p].w));
                *(uint2*)&lk[nxt][r][c4 * 4] = kw;
            }
        }

        // ---- online softmax: 16 in-register values + 2 shuffles ----
        float mx = sacc[0][0];
#pragma unroll
        for (int g = 0; g < 4; ++g)
#pragma unroll
            for (int r = 0; r < 4; ++r) mx = fmaxf(mx, sacc[g][r]);
        mx = fmaxf(mx, __shfl_xor(mx, 16));
        mx = fmaxf(mx, __shfl_xor(mx, 32));
        const float mnew = fmaxf(m_i, mx);
        const float alpha = __builtin_amdgcn_exp2f(m_i - mnew);
        m_i = mnew;

        float ps[4][4];
        float rs = 0.f;
#pragma unroll
        for (int g = 0; g < 4; ++g)
#pragma unroll
            for (int r = 0; r < 4; ++r) {
                ps[g][r] = __builtin_amdgcn_exp2f(sacc[g][r] - m_i);
                rs += ps[g][r];
            }
        rs += __shfl_xor(rs, 16);
        rs += __shfl_xor(rs, 32);
        l_i = l_i * alpha + rs;

        // ---- stage V regs -> lvt[nxt] (V loads covered by QK+stageK+softmax) ----
        if (more) {
            unsigned vh[4][2];
#pragma unroll
            for (int p = 0; p < 4; ++p) {
                vh[p][0] = ubits(pkrtz(vpf[p].x, vpf[p].y));
                vh[p][1] = ubits(pkrtz(vpf[p].z, vpf[p].w));
            }
#pragma unroll
            for (int i = 0; i < 4; ++i) {
                const int jw = i >> 1, sh = (i & 1) * 16;
                uint2 w;
                w.x = ((vh[0][jw] >> sh) & 0xFFFFu) | (((vh[1][jw] >> sh) & 0xFFFFu) << 16);
                w.y = ((vh[2][jw] >> sh) & 0xFFFFu) | (((vh[3][jw] >> sh) & 0xFFFFu) << 16);
                *(uint2*)&lvt[nxt][vt_off(c4 * 4 + i, r16)] = w;
            }
        }

        // ---- rescale O (alpha of rows quad*4+r via shuffle) ----
        float af[4];
#pragma unroll
        for (int r = 0; r < 4; ++r) af[r] = __shfl(alpha, (lane & 48) | (quad * 4 + r));
#pragma unroll
        for (int db = 0; db < 8; ++db)
#pragma unroll
            for (int r = 0; r < 4; ++r) oacc[db][r] *= af[r];

        // ---- O += P.V : A = P (regs), B = V^T from lvt[cur] ----
        f16x4 pf[4];
#pragma unroll
        for (int g = 0; g < 4; ++g)
            pf[g] = (f16x4){(_Float16)ps[g][0], (_Float16)ps[g][1],
                            (_Float16)ps[g][2], (_Float16)ps[g][3]};
#pragma unroll
        for (int db = 0; db < 8; ++db) {
            const int d = db * 16 + l15;
#pragma unroll
            for (int g = 0; g < 4; ++g) {
                f16x4 vb = *(const f16x4*)&lvt[cur][vt_off(d, 4 * g + quad)];
                oacc[db] = __builtin_amdgcn_mfma_f32_16x16x16f16(pf[g], vb, oacc[db], 0, 0, 0);
            }
        }

        __syncthreads();   // single barrier; vmcnt already drained by staging above
    }

    // ---- epilogue ----
    const float inv = 1.0f / l_i;
    float invr[4];
#pragma unroll
    for (int r = 0; r < 4; ++r) invr[r] = __shfl(inv, (lane & 48) | (quad * 4 + r));
#pragma unroll
    for (int db = 0; db < 8; ++db)
#pragma unroll
        for (int r = 0; r < 4; ++r) {
            const int row = qt * QT + wave * 16 + quad * 4 + r;
            const int col = db * 16 + l15;
            Ob[(size_t)row * DH + col] = oacc[db][r] * invr[r];
        }
}

extern "C" void kernel_launch(void* const* d_in, const int* in_sizes, int n_in,
                              void* d_out, int out_size, void* d_ws, size_t ws_size,
                              hipStream_t stream) {
    const float* Q = (const float*)d_in[0];
    const float* K = (const float*)d_in[1];
    const float* V = (const float*)d_in[2];
    float* O = (float*)d_out;
    // masks (d_in[3..5]) and dropout_p (d_in[6]) unused per reference.
    const int nblocks = NB * NH * (SEQ / QT);   // 1024
    fattn_kernel<<<dim3(nblocks), dim3(NTHREADS), 0, stream>>>(Q, K, V, O);
}